// Round 11
// baseline (280.758 us; speedup 1.0000x reference)
//
#include <hip/hip_runtime.h>
#include <hip/hip_bf16.h>
#include <hip/hip_fp16.h>
#include <math.h>

#define NN 262144
#define EE 2097152
#define NPER 32768
#define EPG 262144   // edges per graph
#define EMAX 5120    // max edges per 512-node window (mean 4096, std 63; 16 sigma pad)

typedef float4 f4;
typedef __attribute__((ext_vector_type(4))) float f32x4;
typedef __attribute__((ext_vector_type(8))) _Float16 half8;

// ---------------- binning pass 1 (+ weight prep fused): histogram of dst-windows per chunk
__global__ __launch_bounds__(256) void k_histprep(const int* __restrict__ ei, int* __restrict__ histT,
                                                  const float* __restrict__ emb, const float* __restrict__ W2,
                                                  const float* __restrict__ W3, const float* __restrict__ W1,
                                                  float* __restrict__ M1, _Float16* __restrict__ W3p,
                                                  _Float16* __restrict__ W1p) {
  __shared__ int histl[64];
  int bid = blockIdx.x;
  int t = threadIdx.x;
  if (bid >= 512) {                      // ---- prep branch (22 blocks)
    int pb = bid - 512;
    int q = pb * 256 + t;
    if (pb < 16) {                       // W3 pack: B-frag lane l holds col=l&15, k=kk*32+(l>>4)*8+i
      int jt = q >> 10, kk = (q >> 9) & 1, l = (q >> 3) & 63, i = q & 7;
      int k = kk * 32 + (l >> 4) * 8 + i;
      int j = jt * 16 + (l & 15);
      W3p[q] = (_Float16)W3[k * 64 + j];
    } else if (pb < 20) {                // W1 pack
      int p = q - 4096;
      int kk = p >> 9, l = (p >> 3) & 63, i = p & 7;
      int k = kk * 32 + (l >> 4) * 8 + i;
      W1p[p] = (_Float16)W1[k * 16 + (l & 15)];
    } else {                             // M1 = emb_w @ W2
      int idx = q - 5120;
      int c = idx >> 6, j = idx & 63;
      float acc = 0.f;
      for (int k = 0; k < 64; ++k) acc += emb[c * 64 + k] * W2[k * 64 + j];
      M1[idx] = acc;
    }
    return;
  }
  int g = bid & 7, c = bid >> 3;
  if (t < 64) histl[t] = 0;
  __syncthreads();
  int gN = g * NPER;
  const int4* dst4 = (const int4*)(ei + EE + (size_t)g * EPG + c * 4096);
#pragma unroll
  for (int j = 0; j < 4; ++j) {
    int4 d4 = dst4[j * 256 + t];
    atomicAdd(&histl[(d4.x - gN) >> 9], 1);
    atomicAdd(&histl[(d4.y - gN) >> 9], 1);
    atomicAdd(&histl[(d4.z - gN) >> 9], 1);
    atomicAdd(&histl[(d4.w - gN) >> 9], 1);
  }
  __syncthreads();
  if (t < 64) histT[((size_t)g * 64 + t) * 64 + c] = histl[t];   // [g][w][c]
}

// ---------------- binning pass 2: per-window totals + exact scatter bases (1 wave per graph)
__global__ __launch_bounds__(64) void k_hscan(const int* __restrict__ histT, int* __restrict__ winOff,
                                              int* __restrict__ winCnt, int* __restrict__ baseB) {
  int g = blockIdx.x, w = threadIdx.x;   // 64 threads = 64 windows
  const int* hrow = histT + ((size_t)g * 64 + w) * 64;
  int tot = 0;
#pragma unroll
  for (int c = 0; c < 64; ++c) tot += hrow[c];
  int incl = tot;
#pragma unroll
  for (int o = 1; o < 64; o <<= 1) {
    int u = __shfl_up(incl, o);
    if (w >= o) incl += u;
  }
  int excl = incl - tot;
  int base = g * EPG + excl;
  winOff[g * 64 + w] = base;
  winCnt[g * 64 + w] = tot;
  int run = base;
  for (int c = 0; c < 64; ++c) {
    baseB[((size_t)g * 64 + c) * 64 + w] = run;
    run += hrow[c];
  }
}

// ---------------- binning pass 3: scatter edges into exact window bins (LDS cursors only)
__global__ __launch_bounds__(256) void k_scat(const int* __restrict__ ei, const int* __restrict__ baseB,
                                              int* __restrict__ binned) {
  __shared__ int curl[64];
  int t = threadIdx.x;
  int bid = blockIdx.x;
  int g = bid & 7, c = bid >> 3;
  if (t < 64) curl[t] = baseB[((size_t)g * 64 + c) * 64 + t];
  __syncthreads();
  int gN = g * NPER;
  const int4* src4 = (const int4*)(ei + (size_t)g * EPG + c * 4096);
  const int4* dst4 = (const int4*)(ei + EE + (size_t)g * EPG + c * 4096);
#pragma unroll
  for (int j = 0; j < 4; ++j) {
    int4 s4 = src4[j * 256 + t];
    int4 d4 = dst4[j * 256 + t];
    int dl, w, pos;
    dl = d4.x - gN; w = dl >> 9; pos = atomicAdd(&curl[w], 1); binned[pos] = s4.x | ((dl & 511) << 18);
    dl = d4.y - gN; w = dl >> 9; pos = atomicAdd(&curl[w], 1); binned[pos] = s4.y | ((dl & 511) << 18);
    dl = d4.z - gN; w = dl >> 9; pos = atomicAdd(&curl[w], 1); binned[pos] = s4.z | ((dl & 511) << 18);
    dl = d4.w - gN; w = dl >> 9; pos = atomicAdd(&curl[w], 1); binned[pos] = s4.w | ((dl & 511) << 18);
  }
}

// ---------------- binning pass 4: per-window CSR build fully in LDS (count, scan, fill)
__global__ __launch_bounds__(512) void k_build(const int* __restrict__ binned, const int* __restrict__ winOff,
                                               const int* __restrict__ winCnt, const int* __restrict__ x,
                                               int* __restrict__ offs, int* __restrict__ cnt,
                                               float2* __restrict__ dx, int* __restrict__ adj) {
  __shared__ int ebuf[EMAX];
  __shared__ int cntl[512];
  __shared__ int wsum[8];
  int t = threadIdx.x;
  int bid = blockIdx.x;
  int g = bid & 7, w = bid >> 3;
  int winIdx = g * 64 + w;
  int base = winOff[winIdx];
  int nE = winCnt[winIdx];
  if (nE > EMAX) nE = EMAX;   // statistically impossible; memory safety only
  for (int i = t; i < nE; i += 512) ebuf[i] = binned[base + i];
  cntl[t] = 0;
  __syncthreads();
  for (int i = t; i < nE; i += 512) atomicAdd(&cntl[ebuf[i] >> 18], 1);
  __syncthreads();
  int c = cntl[t];
  int lane = t & 63, wv = t >> 6;
  int incl = c;
#pragma unroll
  for (int o = 1; o < 64; o <<= 1) {
    int u = __shfl_up(incl, o);
    if (lane >= o) incl += u;
  }
  if (lane == 63) wsum[wv] = incl;
  __syncthreads();
  if (t == 0) {
    int r = 0;
#pragma unroll
    for (int i = 0; i < 8; ++i) { int v = wsum[i]; wsum[i] = r; r += v; }
  }
  __syncthreads();
  int ex = incl - c + wsum[wv];
  int node = g * NPER + w * 512 + t;
  offs[node] = base + ex;
  cnt[node] = c;
  float dn = rsqrtf((float)(c + 1));   // +1 self loop
  dx[node] = make_float2(dn, __int_as_float(x[node]));
  cntl[t] = base + ex;                 // reuse as cursor
  __syncthreads();
  for (int i = t; i < nE; i += 512) {
    int v = ebuf[i];
    int pos = atomicAdd(&cntl[v >> 18], 1);
    adj[pos] = v & 0x3FFFF;
  }
}

// ---------------- w8 histogram + out1 per 512-node window (streams binned once)
__global__ __launch_bounds__(512) void k_wout1(const int* __restrict__ binned, const int* __restrict__ winOff,
                                               const int* __restrict__ winCnt, const float2* __restrict__ dx,
                                               const float* __restrict__ M1, const float* __restrict__ b2,
                                               __half2* __restrict__ out1h) {
  __shared__ float w8l[512 * 8];   // 16 KB
  int t = threadIdx.x;
  int bid = blockIdx.x;
  int g = bid & 7, w = bid >> 3;
  int winIdx = g * 64 + w;
  int base = winOff[winIdx];
  int nE = winCnt[winIdx];
#pragma unroll
  for (int i = 0; i < 8; ++i) w8l[i * 512 + t] = 0.f;
  __syncthreads();
  for (int i = t; i < nE; i += 512) {
    int v = __builtin_nontemporal_load(&binned[base + i]);
    int s = v & 0x3FFFF;
    int dl = v >> 18;
    float2 sv = dx[s];                 // (dis[s], x[s] bits) — L2-resident 256KB slice
    atomicAdd(&w8l[dl * 8 + __float_as_int(sv.y)], sv.x);
  }
  __syncthreads();
  int node = g * NPER + w * 512 + t;
  float2 dxn = dx[node];
  float dn = dxn.x;
  int xc = __float_as_int(dxn.y);
  float wv[8];
#pragma unroll
  for (int c = 0; c < 8; ++c) wv[c] = (w8l[t * 8 + c] + ((c == xc) ? dn : 0.f)) * dn;
  __half2 orow[32];
#pragma unroll
  for (int j2 = 0; j2 < 32; ++j2) {
    float oa = b2[j2 * 2], ob = b2[j2 * 2 + 1];
#pragma unroll
    for (int c = 0; c < 8; ++c) {      // M1/b2 wave-uniform -> scalar loads
      oa += wv[c] * M1[c * 64 + j2 * 2];
      ob += wv[c] * M1[c * 64 + j2 * 2 + 1];
    }
    orow[j2] = __floats2half2_rn(fmaxf(oa, 0.f) * dn, fmaxf(ob, 0.f) * dn);
  }
  f4* dstp = (f4*)(out1h + (size_t)node * 32);
  const f4* srcp = (const f4*)orow;
#pragma unroll
  for (int q = 0; q < 8; ++q) dstp[q] = srcp[q];
}

// ---------------- layer 2: CSR gather (8-deep, pk-f16 accum) + MFMA(W3) + relu + MFMA(W1) + softmax
__global__ __launch_bounds__(256) void k_layer2(const int* __restrict__ adj, const int* __restrict__ offs,
                                                const int* __restrict__ cnt, const float2* __restrict__ dx,
                                                const __half2* __restrict__ out1h,
                                                const _Float16* __restrict__ W3p, const float* __restrict__ b3,
                                                const _Float16* __restrict__ W1p, const float* __restrict__ b1,
                                                float* __restrict__ dout, __half* __restrict__ sbh) {
  __shared__ _Float16 aggh[16 * 64];   // [node][k] f16, XOR-swizzled rows (2 KB)
  __shared__ _Float16 o2h[16 * 64];    // [node][j] f16, XOR-swizzled rows (2 KB)
  int tid = threadIdx.x;
  int bid = blockIdx.x;
  int swz = (bid & 7) * 2048 + (bid >> 3);
  int lane = tid & 63;
  int w = tid >> 6;                    // wave id 0..3
  int sub = lane >> 4, part = lane & 15;
  int ndl = (w << 2) + sub;            // node-local 0..15
  int node = swz * 16 + ndl;

  // phase 1: agg = dn * sum(out1h[self] + out1h[neighbors]) — packed f16 accumulation.
  // adj is pure stream (nontemporal); out1h gathers want L2 residency (normal loads).
  float dn = dx[node].x;
  int off = offs[node];
  int c = cnt[node];
  const __half2* sp = out1h + ((size_t)node << 5) + (part << 1);
  __half2 a01 = sp[0], a23 = sp[1];    // self (prescaled by dis[src])
  int it = 0;
  for (; it + 8 <= c; it += 8) {
    int sA[8];
#pragma unroll
    for (int u = 0; u < 8; ++u) sA[u] = __builtin_nontemporal_load(&adj[off + it + u]);
#pragma unroll
    for (int u = 0; u < 8; ++u) {
      const __half2* hp = out1h + (((size_t)sA[u]) << 5) + (part << 1);
      __half2 h0 = hp[0], h1 = hp[1];
      a01 = __hadd2(a01, h0);
      a23 = __hadd2(a23, h1);
    }
  }
  for (; it < c; ++it) {
    int s = __builtin_nontemporal_load(&adj[off + it]);
    const __half2* hp = out1h + (((size_t)s) << 5) + (part << 1);
    __half2 h0 = hp[0], h1 = hp[1];
    a01 = __hadd2(a01, h0);
    a23 = __hadd2(a23, h1);
  }
  {
    __half2 dn2 = __float2half2_rn(dn);
    a01 = __hmul2(a01, dn2);
    a23 = __hmul2(a23, dn2);
    int byte = (ndl * 128 + part * 8) ^ ((ndl & 7) << 4);
    *(__half2*)((char*)aggh + byte) = a01;
    *(__half2*)((char*)aggh + byte + 4) = a23;
  }
  __syncthreads();

  // phase 3a: o2 = relu(agg @ W3 + b3), wave w owns W3 cols [16w,16w+16)
  f32x4 acc = {0.f, 0.f, 0.f, 0.f};
#pragma unroll
  for (int kk = 0; kk < 2; ++kk) {
    int row = lane & 15;
    int abyte = (row * 128 + kk * 64 + (lane >> 4) * 16) ^ ((row & 7) << 4);
    half8 afrag = *(const half8*)((const char*)aggh + abyte);
    half8 bfrag = *(const half8*)&W3p[((w * 2 + kk) * 64 + lane) * 8];
    acc = __builtin_amdgcn_mfma_f32_16x16x32_f16(afrag, bfrag, acc, 0, 0, 0);
  }
  {
    int colj = w * 16 + (lane & 15);
    float b3v = b3[colj];
#pragma unroll
    for (int r = 0; r < 4; ++r) {
      int nrow = (lane >> 4) * 4 + r;                    // node 0..15
      _Float16 hv = (_Float16)fmaxf(acc[r] + b3v, 0.f);
      int byte = (nrow * 128 + colj * 2) ^ ((nrow & 7) << 4);
      *(_Float16*)((char*)o2h + byte) = hv;
    }
  }
  __syncthreads();

  // phase 3b: s = o2 @ W1 + b1 (each wave computes full 16x16; wave w stores node%4==w rows)
  f32x4 acc2 = {0.f, 0.f, 0.f, 0.f};
#pragma unroll
  for (int kk = 0; kk < 2; ++kk) {
    int row = lane & 15;
    int abyte = (row * 128 + kk * 64 + (lane >> 4) * 16) ^ ((row & 7) << 4);
    half8 afrag = *(const half8*)((const char*)o2h + abyte);
    half8 bfrag = *(const half8*)&W1p[(kk * 64 + lane) * 8];
    acc2 = __builtin_amdgcn_mfma_f32_16x16x32_f16(afrag, bfrag, acc2, 0, 0, 0);
  }
  {
    float sv = acc2[w] + b1[lane & 15];                  // this wave's reg r=w: node=(lane>>4)*4+w
    float mx = sv;
#pragma unroll
    for (int m = 1; m < 16; m <<= 1) mx = fmaxf(mx, __shfl_xor(mx, m));
    float ex = expf(sv - mx);
    float sm = ex;
#pragma unroll
    for (int m = 1; m < 16; m <<= 1) sm += __shfl_xor(sm, m);
    float so = ex / sm;
    int nrow = (lane >> 4) * 4 + w;
    // dout: never re-read on device -> nontemporal (keeps L2 clean for out1h gather)
    __builtin_nontemporal_store(so, &dout[8 + (size_t)swz * 256 + nrow * 16 + (lane & 15)]);
    // sbh: gathered by k_num + streamed by k_ssden -> NORMAL store (1 MB/graph stays in L2)
    sbh[((swz * 16 + nrow) << 4) + (lane & 15)] = __float2half(so);
  }
}

// ---------------- mincut num + den via CSR over fp16 s (8 lanes/node, 32 nodes/block)
__global__ __launch_bounds__(256) void k_num(const int* __restrict__ adj, const int* __restrict__ offs,
                                             const int* __restrict__ cnt, const __half2* __restrict__ sbh2,
                                             float* __restrict__ numP, float* __restrict__ denP) {
  __shared__ float redn[32];
  __shared__ float redd[32];
  int tid = threadIdx.x;
  int bid = blockIdx.x;                 // 8192 blocks
  int swz = (bid & 7) * 1024 + (bid >> 3);
  int grp = tid >> 3, t8 = tid & 7;
  int node = swz * 32 + grp;
  int off = offs[node];
  int c = cnt[node];
  float svx = 0.f, svy = 0.f, sq = 0.f;
  int it = 0;
  for (; it + 8 <= c; it += 8) {
    int sA[8];
#pragma unroll
    for (int u = 0; u < 8; ++u) sA[u] = __builtin_nontemporal_load(&adj[off + it + u]);
#pragma unroll
    for (int u = 0; u < 8; ++u) {
      float2 v = __half22float2(sbh2[(sA[u] << 3) + t8]);
      svx += v.x; svy += v.y; sq += v.x * v.x + v.y * v.y;
    }
  }
  for (; it < c; ++it) {
    int s = __builtin_nontemporal_load(&adj[off + it]);
    float2 v = __half22float2(sbh2[(s << 3) + t8]);
    svx += v.x; svy += v.y; sq += v.x * v.x + v.y * v.y;
  }
  float2 sf = __half22float2(sbh2[(node << 3) + t8]);
  float dot = sf.x * svx + sf.y * svy;
#pragma unroll
  for (int m = 1; m < 8; m <<= 1) {
    dot += __shfl_xor(dot, m);
    sq  += __shfl_xor(sq, m);
  }
  if (t8 == 0) { redn[grp] = dot; redd[grp] = sq; }
  __syncthreads();
  if (tid < 32) {
    float a = redn[tid], d = redd[tid];
#pragma unroll
    for (int m = 1; m < 32; m <<= 1) {
      a += __shfl_xor(a, m);
      d += __shfl_xor(d, m);
    }
    if (tid == 0) { numP[swz] = a; denP[swz] = d; }
  }
}

// ---------------- xp + SS per graph from f16 s -> per-block partials (NO global atomics)
__global__ __launch_bounds__(256) void k_ssden(const __half2* __restrict__ sbh2,
                                               float* __restrict__ xpP, float* __restrict__ SSp) {
  __shared__ float sl[256 * 17];
  __shared__ float xpl[16];
  int t = threadIdx.x;
  int b = blockIdx.x;
  int t1 = t >> 4, t2 = t & 15;
  if (t < 16) xpl[t] = 0.f;
  int node = b * 256 + t;
  const __half2* pr = sbh2 + ((size_t)node << 3);
  float* row = &sl[t * 17];
#pragma unroll
  for (int q = 0; q < 8; ++q) {
    float2 v = __half22float2(pr[q]);
    row[q * 2] = v.x;
    row[q * 2 + 1] = v.y;
  }
  __syncthreads();
  float ss = 0.f;
  for (int n = 0; n < 256; ++n) ss += sl[n * 17 + t1] * sl[n * 17 + t2];
  SSp[(size_t)b * 256 + t] = ss;
  float colsum = 0.f;
#pragma unroll
  for (int r = 0; r < 16; ++r) colsum += sl[(t1 * 16 + r) * 17 + t2];
  atomicAdd(&xpl[t2], colsum);           // LDS atomic (cheap)
  __syncthreads();
  if (t < 16) xpP[b * 16 + t] = xpl[t];
}

// ---------------- reduce partials into accum + per-graph o1 (8 blocks, one per graph)
// accum layout: [num 8][den 8][xp 128][o1g 8]  (152 floats)
__global__ __launch_bounds__(256) void k_red(const float* __restrict__ numP, const float* __restrict__ denP,
                                             const float* __restrict__ SSp, const float* __restrict__ xpP,
                                             float* __restrict__ accum) {
  __shared__ float r1[256], r2[256];
  __shared__ float bc;
  int g = blockIdx.x, t = threadIdx.x;
  float acc = 0.f;
  for (int b = 0; b < 128; ++b) acc += SSp[((size_t)(g * 128 + b)) * 256 + t];
  float a = 0.f, d = 0.f;
  for (int i = 0; i < 4; ++i) {
    a += numP[g * 1024 + i * 256 + t];
    d += denP[g * 1024 + i * 256 + t];
  }
  r1[t] = a; r2[t] = d;
  __syncthreads();
  for (int off = 128; off > 0; off >>= 1) {
    if (t < off) { r1[t] += r1[t + off]; r2[t] += r2[t + off]; }
    __syncthreads();
  }
  if (t == 0) { accum[g] = r1[0]; accum[8 + g] = r2[0]; }
  if (t < 16) {
    float s = 0.f;
    for (int b = 0; b < 128; ++b) s += xpP[(g * 128 + b) * 16 + t];
    accum[16 + g * 16 + t] = s;
  }
  __syncthreads();
  r1[t] = acc * acc;
  __syncthreads();
  for (int off = 128; off > 0; off >>= 1) {
    if (t < off) r1[t] += r1[t + off];
    __syncthreads();
  }
  if (t == 0) bc = sqrtf(r1[0]);
  __syncthreads();
  float dv = acc / bc - (((t >> 4) == (t & 15)) ? 0.25f : 0.f);
  r1[t] = dv * dv;
  __syncthreads();
  for (int off = 128; off > 0; off >>= 1) {
    if (t < off) r1[t] += r1[t + off];
    __syncthreads();
  }
  if (t == 0) accum[144 + g] = sqrtf(r1[0]);
}

// ---------------- scalars: mc1, o1, pred (tiny)
__global__ __launch_bounds__(64) void k_final(const float* __restrict__ accum, const float* __restrict__ ncells,
                                              const float* __restrict__ Wp, const float* __restrict__ bp,
                                              float* __restrict__ dout) {
  int t = threadIdx.x;
  const float* num = accum;
  const float* den = accum + 8;
  const float* xp  = accum + 16;
  const float* o1g = accum + 144;
  if (t == 0) {
    float m = 0.f, o = 0.f;
    for (int g = 0; g < 8; ++g) { m += -num[g] / den[g]; o += o1g[g]; }
    dout[8 + (size_t)NN * 16] = m / 8.f;
    dout[8 + (size_t)NN * 16 + 1] = o / 8.f;
  }
  if (t < 8) {
    float p = bp[0];
    for (int k = 0; k < 16; ++k) p += (xp[t * 16 + k] / ncells[t]) * Wp[k];
    dout[t] = p;
  }
}

extern "C" void kernel_launch(void* const* d_in, const int* in_sizes, int n_in,
                              void* d_out, int out_size, void* d_ws, size_t ws_size,
                              hipStream_t stream) {
  const int* x            = (const int*)d_in[0];
  const int* ei           = (const int*)d_in[1];   // int32 (JAX x64 disabled)
  const float* ncells     = (const float*)d_in[3];
  const float* emb        = (const float*)d_in[4];
  const float* W2         = (const float*)d_in[5];
  const float* b2         = (const float*)d_in[6];
  const float* W3         = (const float*)d_in[7];
  const float* b3         = (const float*)d_in[8];
  const float* W1         = (const float*)d_in[9];
  const float* b1         = (const float*)d_in[10];
  const float* Wp         = (const float*)d_in[11];
  const float* bp         = (const float*)d_in[12];
  float* dout = (float*)d_out;

  // workspace layout (~58 MB); every cell fully written before read each launch (no memset).
  char* w = (char*)d_ws;
  float* accum = (float*)w;                            // 152 used, pad 160
  float2* dx   = (float2*)(accum + 160);               // N float2 (dis, x-bits)
  int* offs    = (int*)(dx + NN);                      // N
  int* cnt     = offs + NN;                            // N
  int* adj     = cnt + NN;                             // E
  float* M1    = (float*)(adj + EE);                   // 512
  _Float16* W3p = (_Float16*)(M1 + 512);               // 4096 halves
  _Float16* W1p = W3p + 4096;                          // 1024 halves
  __half2* out1h = (__half2*)(W1p + 1024);             // N*32 half2 = 32 MB
  __half* sbh  = (__half*)(out1h + (size_t)NN * 32);   // N*16 half = 8 MB
  float* numP  = (float*)(sbh + (size_t)NN * 16);      // 8192
  float* denP  = numP + 8192;                          // 8192
  float* SSp   = denP + 8192;                          // 1024*256
  float* xpP   = SSp + 1024 * 256;                     // 1024*16
  int* histT   = (int*)(xpP + 1024 * 16);              // 8*64*64
  int* baseB   = histT + 8 * 64 * 64;                  // 8*64*64
  int* winOff  = baseB + 8 * 64 * 64;                  // 512
  int* winCnt  = winOff + 512;                         // 512
  int* binned  = winCnt + 512;                         // E

  k_histprep<<<534, 256, 0, stream>>>(ei, histT, emb, W2, W3, W1, M1, W3p, W1p);
  k_hscan <<<8, 64, 0, stream>>>(histT, winOff, winCnt, baseB);
  k_scat  <<<512, 256, 0, stream>>>(ei, baseB, binned);
  k_build <<<512, 512, 0, stream>>>(binned, winOff, winCnt, x, offs, cnt, dx, adj);
  k_wout1 <<<512, 512, 0, stream>>>(binned, winOff, winCnt, dx, M1, b2, out1h);
  k_layer2<<<16384, 256, 0, stream>>>(adj, offs, cnt, dx, out1h, W3p, b3, W1p, b1, dout, sbh);
  k_num   <<<8192, 256, 0, stream>>>(adj, offs, cnt, (const __half2*)sbh, numP, denP);
  k_ssden <<<1024, 256, 0, stream>>>((const __half2*)sbh, xpP, SSp);
  k_red   <<<8, 256, 0, stream>>>(numP, denP, SSp, xpP, accum);
  k_final <<<1, 64, 0, stream>>>(accum, ncells, Wp, bp, dout);
}

// Round 13
// 270.600 us; speedup vs baseline: 1.0375x; 1.0375x over previous
//
#include <hip/hip_runtime.h>
#include <hip/hip_bf16.h>
#include <hip/hip_fp16.h>
#include <math.h>

#define NN 262144
#define EE 2097152
#define NPER 32768
#define EPG 262144   // edges per graph
#define EMAX 5120    // max edges per 512-node window (mean 4096, std 63; 16 sigma pad)

typedef float4 f4;
typedef __attribute__((ext_vector_type(4))) float f32x4;
typedef __attribute__((ext_vector_type(8))) _Float16 half8;

// ---------------- binning pass 1 (+ weight prep fused): histogram of dst-windows per chunk
__global__ __launch_bounds__(256) void k_histprep(const int* __restrict__ ei, int* __restrict__ histT,
                                                  const float* __restrict__ emb, const float* __restrict__ W2,
                                                  const float* __restrict__ W3, const float* __restrict__ W1,
                                                  float* __restrict__ M1, _Float16* __restrict__ W3p,
                                                  _Float16* __restrict__ W1p) {
  __shared__ int histl[64];
  int bid = blockIdx.x;
  int t = threadIdx.x;
  if (bid >= 512) {                      // ---- prep branch (22 blocks)
    int pb = bid - 512;
    int q = pb * 256 + t;
    if (pb < 16) {                       // W3 pack: B-frag lane l holds col=l&15, k=kk*32+(l>>4)*8+i
      int jt = q >> 10, kk = (q >> 9) & 1, l = (q >> 3) & 63, i = q & 7;
      int k = kk * 32 + (l >> 4) * 8 + i;
      int j = jt * 16 + (l & 15);
      W3p[q] = (_Float16)W3[k * 64 + j];
    } else if (pb < 20) {                // W1 pack
      int p = q - 4096;
      int kk = p >> 9, l = (p >> 3) & 63, i = p & 7;
      int k = kk * 32 + (l >> 4) * 8 + i;
      W1p[p] = (_Float16)W1[k * 16 + (l & 15)];
    } else {                             // M1 = emb_w @ W2
      int idx = q - 5120;
      int c = idx >> 6, j = idx & 63;
      float acc = 0.f;
      for (int k = 0; k < 64; ++k) acc += emb[c * 64 + k] * W2[k * 64 + j];
      M1[idx] = acc;
    }
    return;
  }
  int g = bid & 7, c = bid >> 3;
  if (t < 64) histl[t] = 0;
  __syncthreads();
  int gN = g * NPER;
  const int4* dst4 = (const int4*)(ei + EE + (size_t)g * EPG + c * 4096);
#pragma unroll
  for (int j = 0; j < 4; ++j) {
    int4 d4 = dst4[j * 256 + t];
    atomicAdd(&histl[(d4.x - gN) >> 9], 1);
    atomicAdd(&histl[(d4.y - gN) >> 9], 1);
    atomicAdd(&histl[(d4.z - gN) >> 9], 1);
    atomicAdd(&histl[(d4.w - gN) >> 9], 1);
  }
  __syncthreads();
  if (t < 64) histT[((size_t)g * 64 + t) * 64 + c] = histl[t];   // [g][w][c]
}

// ---------------- binning pass 2: per-window totals + exact scatter bases (1 wave per graph)
__global__ __launch_bounds__(64) void k_hscan(const int* __restrict__ histT, int* __restrict__ winOff,
                                              int* __restrict__ winCnt, int* __restrict__ baseB) {
  int g = blockIdx.x, w = threadIdx.x;   // 64 threads = 64 windows
  const int* hrow = histT + ((size_t)g * 64 + w) * 64;
  int tot = 0;
#pragma unroll
  for (int c = 0; c < 64; ++c) tot += hrow[c];
  int incl = tot;
#pragma unroll
  for (int o = 1; o < 64; o <<= 1) {
    int u = __shfl_up(incl, o);
    if (w >= o) incl += u;
  }
  int excl = incl - tot;
  int base = g * EPG + excl;
  winOff[g * 64 + w] = base;
  winCnt[g * 64 + w] = tot;
  int run = base;
  for (int c = 0; c < 64; ++c) {
    baseB[((size_t)g * 64 + c) * 64 + w] = run;
    run += hrow[c];
  }
}

// ---------------- binning pass 3: scatter edges into exact window bins (LDS cursors only)
__global__ __launch_bounds__(256) void k_scat(const int* __restrict__ ei, const int* __restrict__ baseB,
                                              int* __restrict__ binned) {
  __shared__ int curl[64];
  int t = threadIdx.x;
  int bid = blockIdx.x;
  int g = bid & 7, c = bid >> 3;
  if (t < 64) curl[t] = baseB[((size_t)g * 64 + c) * 64 + t];
  __syncthreads();
  int gN = g * NPER;
  const int4* src4 = (const int4*)(ei + (size_t)g * EPG + c * 4096);
  const int4* dst4 = (const int4*)(ei + EE + (size_t)g * EPG + c * 4096);
#pragma unroll
  for (int j = 0; j < 4; ++j) {
    int4 s4 = src4[j * 256 + t];
    int4 d4 = dst4[j * 256 + t];
    int dl, w, pos;
    dl = d4.x - gN; w = dl >> 9; pos = atomicAdd(&curl[w], 1); binned[pos] = s4.x | ((dl & 511) << 18);
    dl = d4.y - gN; w = dl >> 9; pos = atomicAdd(&curl[w], 1); binned[pos] = s4.y | ((dl & 511) << 18);
    dl = d4.z - gN; w = dl >> 9; pos = atomicAdd(&curl[w], 1); binned[pos] = s4.z | ((dl & 511) << 18);
    dl = d4.w - gN; w = dl >> 9; pos = atomicAdd(&curl[w], 1); binned[pos] = s4.w | ((dl & 511) << 18);
  }
}

// ---------------- binning pass 4: per-window CSR build fully in LDS (count, scan, fill)
__global__ __launch_bounds__(512) void k_build(const int* __restrict__ binned, const int* __restrict__ winOff,
                                               const int* __restrict__ winCnt, const int* __restrict__ x,
                                               int* __restrict__ offs, int* __restrict__ cnt,
                                               float2* __restrict__ dx, int* __restrict__ adj) {
  __shared__ int ebuf[EMAX];
  __shared__ int cntl[512];
  __shared__ int wsum[8];
  int t = threadIdx.x;
  int bid = blockIdx.x;
  int g = bid & 7, w = bid >> 3;
  int winIdx = g * 64 + w;
  int base = winOff[winIdx];
  int nE = winCnt[winIdx];
  if (nE > EMAX) nE = EMAX;   // statistically impossible; memory safety only
  for (int i = t; i < nE; i += 512) ebuf[i] = binned[base + i];
  cntl[t] = 0;
  __syncthreads();
  for (int i = t; i < nE; i += 512) atomicAdd(&cntl[ebuf[i] >> 18], 1);
  __syncthreads();
  int c = cntl[t];
  int lane = t & 63, wv = t >> 6;
  int incl = c;
#pragma unroll
  for (int o = 1; o < 64; o <<= 1) {
    int u = __shfl_up(incl, o);
    if (lane >= o) incl += u;
  }
  if (lane == 63) wsum[wv] = incl;
  __syncthreads();
  if (t == 0) {
    int r = 0;
#pragma unroll
    for (int i = 0; i < 8; ++i) { int v = wsum[i]; wsum[i] = r; r += v; }
  }
  __syncthreads();
  int ex = incl - c + wsum[wv];
  int node = g * NPER + w * 512 + t;
  offs[node] = base + ex;
  cnt[node] = c;
  float dn = rsqrtf((float)(c + 1));   // +1 self loop
  dx[node] = make_float2(dn, __int_as_float(x[node]));
  cntl[t] = base + ex;                 // reuse as cursor
  __syncthreads();
  for (int i = t; i < nE; i += 512) {
    int v = ebuf[i];
    int pos = atomicAdd(&cntl[v >> 18], 1);
    adj[pos] = v & 0x3FFFF;
  }
}

// ---------------- w8 histogram + out1 per 512-node window (streams binned once, 4-deep pipeline)
__global__ __launch_bounds__(512) void k_wout1(const int* __restrict__ binned, const int* __restrict__ winOff,
                                               const int* __restrict__ winCnt, const float2* __restrict__ dx,
                                               const float* __restrict__ M1, const float* __restrict__ b2,
                                               __half2* __restrict__ out1h) {
  __shared__ float w8l[512 * 8];   // 16 KB
  int t = threadIdx.x;
  int bid = blockIdx.x;
  int g = bid & 7, w = bid >> 3;
  int winIdx = g * 64 + w;
  int base = winOff[winIdx];
  int nE = winCnt[winIdx];
#pragma unroll
  for (int i = 0; i < 8; ++i) w8l[i * 512 + t] = 0.f;
  __syncthreads();
  // 4-deep software pipeline: 4 coalesced loads -> 4 independent gathers -> 4 LDS atomics.
  for (int i = t; i < nE; i += 2048) {
    int i1 = i + 512, i2 = i + 1024, i3 = i + 1536;
    int v0 = binned[base + i];
    int v1 = (i1 < nE) ? binned[base + i1] : -1;
    int v2 = (i2 < nE) ? binned[base + i2] : -1;
    int v3 = (i3 < nE) ? binned[base + i3] : -1;
    float2 s0 = dx[v0 & 0x3FFFF];
    float2 s1 = (v1 >= 0) ? dx[v1 & 0x3FFFF] : make_float2(0.f, 0.f);
    float2 s2 = (v2 >= 0) ? dx[v2 & 0x3FFFF] : make_float2(0.f, 0.f);
    float2 s3 = (v3 >= 0) ? dx[v3 & 0x3FFFF] : make_float2(0.f, 0.f);
    atomicAdd(&w8l[(v0 >> 18) * 8 + __float_as_int(s0.y)], s0.x);
    if (v1 >= 0) atomicAdd(&w8l[(v1 >> 18) * 8 + __float_as_int(s1.y)], s1.x);
    if (v2 >= 0) atomicAdd(&w8l[(v2 >> 18) * 8 + __float_as_int(s2.y)], s2.x);
    if (v3 >= 0) atomicAdd(&w8l[(v3 >> 18) * 8 + __float_as_int(s3.y)], s3.x);
  }
  __syncthreads();
  int node = g * NPER + w * 512 + t;
  float2 dxn = dx[node];
  float dn = dxn.x;
  int xc = __float_as_int(dxn.y);
  float wv[8];
#pragma unroll
  for (int c = 0; c < 8; ++c) wv[c] = (w8l[t * 8 + c] + ((c == xc) ? dn : 0.f)) * dn;
  __half2 orow[32];
#pragma unroll
  for (int j2 = 0; j2 < 32; ++j2) {
    float oa = b2[j2 * 2], ob = b2[j2 * 2 + 1];
#pragma unroll
    for (int c = 0; c < 8; ++c) {      // M1/b2 wave-uniform -> scalar loads
      oa += wv[c] * M1[c * 64 + j2 * 2];
      ob += wv[c] * M1[c * 64 + j2 * 2 + 1];
    }
    orow[j2] = __floats2half2_rn(fmaxf(oa, 0.f) * dn, fmaxf(ob, 0.f) * dn);
  }
  f4* dstp = (f4*)(out1h + (size_t)node * 32);
  const f4* srcp = (const f4*)orow;
#pragma unroll
  for (int q = 0; q < 8; ++q) dstp[q] = srcp[q];
}

// ---------------- layer 2: CSR gather (8-deep, pk-f16 accum) + MFMA(W3) + relu + MFMA(W1) + softmax
__global__ __launch_bounds__(256) void k_layer2(const int* __restrict__ adj, const int* __restrict__ offs,
                                                const int* __restrict__ cnt, const float2* __restrict__ dx,
                                                const __half2* __restrict__ out1h,
                                                const _Float16* __restrict__ W3p, const float* __restrict__ b3,
                                                const _Float16* __restrict__ W1p, const float* __restrict__ b1,
                                                float* __restrict__ dout, __half* __restrict__ sbh) {
  __shared__ _Float16 aggh[16 * 64];   // [node][k] f16, XOR-swizzled rows (2 KB)
  __shared__ _Float16 o2h[16 * 64];    // [node][j] f16, XOR-swizzled rows (2 KB)
  int tid = threadIdx.x;
  int bid = blockIdx.x;
  int swz = (bid & 7) * 2048 + (bid >> 3);
  int lane = tid & 63;
  int w = tid >> 6;                    // wave id 0..3
  int sub = lane >> 4, part = lane & 15;
  int ndl = (w << 2) + sub;            // node-local 0..15
  int node = swz * 16 + ndl;

  // phase 1: agg = dn * sum(out1h[self] + out1h[neighbors]) — packed f16 accumulation
  float dn = dx[node].x;
  int off = offs[node];
  int c = cnt[node];
  const __half2* sp = out1h + ((size_t)node << 5) + (part << 1);
  __half2 a01 = sp[0], a23 = sp[1];    // self (prescaled by dis[src])
  int it = 0;
  for (; it + 8 <= c; it += 8) {
    int sA[8];
#pragma unroll
    for (int u = 0; u < 8; ++u) sA[u] = adj[off + it + u];
#pragma unroll
    for (int u = 0; u < 8; ++u) {
      const __half2* hp = out1h + (((size_t)sA[u]) << 5) + (part << 1);
      __half2 h0 = hp[0], h1 = hp[1];
      a01 = __hadd2(a01, h0);
      a23 = __hadd2(a23, h1);
    }
  }
  for (; it < c; ++it) {
    int s = adj[off + it];
    const __half2* hp = out1h + (((size_t)s) << 5) + (part << 1);
    __half2 h0 = hp[0], h1 = hp[1];
    a01 = __hadd2(a01, h0);
    a23 = __hadd2(a23, h1);
  }
  {
    __half2 dn2 = __float2half2_rn(dn);
    a01 = __hmul2(a01, dn2);
    a23 = __hmul2(a23, dn2);
    int byte = (ndl * 128 + part * 8) ^ ((ndl & 7) << 4);
    *(__half2*)((char*)aggh + byte) = a01;
    *(__half2*)((char*)aggh + byte + 4) = a23;
  }
  __syncthreads();

  // phase 3a: o2 = relu(agg @ W3 + b3), wave w owns W3 cols [16w,16w+16)
  f32x4 acc = {0.f, 0.f, 0.f, 0.f};
#pragma unroll
  for (int kk = 0; kk < 2; ++kk) {
    int row = lane & 15;
    int abyte = (row * 128 + kk * 64 + (lane >> 4) * 16) ^ ((row & 7) << 4);
    half8 afrag = *(const half8*)((const char*)aggh + abyte);
    half8 bfrag = *(const half8*)&W3p[((w * 2 + kk) * 64 + lane) * 8];
    acc = __builtin_amdgcn_mfma_f32_16x16x32_f16(afrag, bfrag, acc, 0, 0, 0);
  }
  {
    int colj = w * 16 + (lane & 15);
    float b3v = b3[colj];
#pragma unroll
    for (int r = 0; r < 4; ++r) {
      int nrow = (lane >> 4) * 4 + r;                    // node 0..15
      _Float16 hv = (_Float16)fmaxf(acc[r] + b3v, 0.f);
      int byte = (nrow * 128 + colj * 2) ^ ((nrow & 7) << 4);
      *(_Float16*)((char*)o2h + byte) = hv;
    }
  }
  __syncthreads();

  // phase 3b: s = o2 @ W1 + b1 (each wave computes full 16x16; wave w stores node%4==w rows)
  f32x4 acc2 = {0.f, 0.f, 0.f, 0.f};
#pragma unroll
  for (int kk = 0; kk < 2; ++kk) {
    int row = lane & 15;
    int abyte = (row * 128 + kk * 64 + (lane >> 4) * 16) ^ ((row & 7) << 4);
    half8 afrag = *(const half8*)((const char*)o2h + abyte);
    half8 bfrag = *(const half8*)&W1p[(kk * 64 + lane) * 8];
    acc2 = __builtin_amdgcn_mfma_f32_16x16x32_f16(afrag, bfrag, acc2, 0, 0, 0);
  }
  {
    float sv = acc2[w] + b1[lane & 15];                  // this wave's reg r=w: node=(lane>>4)*4+w
    float mx = sv;
#pragma unroll
    for (int m = 1; m < 16; m <<= 1) mx = fmaxf(mx, __shfl_xor(mx, m));
    float ex = expf(sv - mx);
    float sm = ex;
#pragma unroll
    for (int m = 1; m < 16; m <<= 1) sm += __shfl_xor(sm, m);
    float so = ex / sm;
    int nrow = (lane >> 4) * 4 + w;
    // dout: never re-read on device -> nontemporal STORE (write-no-allocate keeps L2 clean)
    __builtin_nontemporal_store(so, &dout[8 + (size_t)swz * 256 + nrow * 16 + (lane & 15)]);
    // sbh: gathered by k_num + streamed by k_ssden -> NORMAL store (1 MB/graph stays in L2)
    sbh[((swz * 16 + nrow) << 4) + (lane & 15)] = __float2half(so);
  }
}

// ---------------- mincut num + den via CSR over fp16 s (8 lanes/node, 32 nodes/block)
__global__ __launch_bounds__(256) void k_num(const int* __restrict__ adj, const int* __restrict__ offs,
                                             const int* __restrict__ cnt, const __half2* __restrict__ sbh2,
                                             float* __restrict__ numP, float* __restrict__ denP) {
  __shared__ float redn[32];
  __shared__ float redd[32];
  int tid = threadIdx.x;
  int bid = blockIdx.x;                 // 8192 blocks
  int swz = (bid & 7) * 1024 + (bid >> 3);
  int grp = tid >> 3, t8 = tid & 7;
  int node = swz * 32 + grp;
  int off = offs[node];
  int c = cnt[node];
  float svx = 0.f, svy = 0.f, sq = 0.f;
  int it = 0;
  for (; it + 8 <= c; it += 8) {
    int sA[8];
#pragma unroll
    for (int u = 0; u < 8; ++u) sA[u] = adj[off + it + u];
#pragma unroll
    for (int u = 0; u < 8; ++u) {
      float2 v = __half22float2(sbh2[(sA[u] << 3) + t8]);
      svx += v.x; svy += v.y; sq += v.x * v.x + v.y * v.y;
    }
  }
  for (; it < c; ++it) {
    float2 v = __half22float2(sbh2[(adj[off + it] << 3) + t8]);
    svx += v.x; svy += v.y; sq += v.x * v.x + v.y * v.y;
  }
  float2 sf = __half22float2(sbh2[(node << 3) + t8]);
  float dot = sf.x * svx + sf.y * svy;
#pragma unroll
  for (int m = 1; m < 8; m <<= 1) {
    dot += __shfl_xor(dot, m);
    sq  += __shfl_xor(sq, m);
  }
  if (t8 == 0) { redn[grp] = dot; redd[grp] = sq; }
  __syncthreads();
  if (tid < 32) {
    float a = redn[tid], d = redd[tid];
#pragma unroll
    for (int m = 1; m < 32; m <<= 1) {
      a += __shfl_xor(a, m);
      d += __shfl_xor(d, m);
    }
    if (tid == 0) { numP[swz] = a; denP[swz] = d; }
  }
}

// ---------------- xp + SS per graph from f16 s -> per-block partials (NO global atomics)
__global__ __launch_bounds__(256) void k_ssden(const __half2* __restrict__ sbh2,
                                               float* __restrict__ xpP, float* __restrict__ SSp) {
  __shared__ float sl[256 * 17];
  __shared__ float xpl[16];
  int t = threadIdx.x;
  int b = blockIdx.x;
  int t1 = t >> 4, t2 = t & 15;
  if (t < 16) xpl[t] = 0.f;
  int node = b * 256 + t;
  const __half2* pr = sbh2 + ((size_t)node << 3);
  float* row = &sl[t * 17];
#pragma unroll
  for (int q = 0; q < 8; ++q) {
    float2 v = __half22float2(pr[q]);
    row[q * 2] = v.x;
    row[q * 2 + 1] = v.y;
  }
  __syncthreads();
  float ss = 0.f;
  for (int n = 0; n < 256; ++n) ss += sl[n * 17 + t1] * sl[n * 17 + t2];
  SSp[(size_t)b * 256 + t] = ss;
  float colsum = 0.f;
#pragma unroll
  for (int r = 0; r < 16; ++r) colsum += sl[(t1 * 16 + r) * 17 + t2];
  atomicAdd(&xpl[t2], colsum);           // LDS atomic (cheap)
  __syncthreads();
  if (t < 16) xpP[b * 16 + t] = xpl[t];
}

// ---------------- reduce partials into accum + per-graph o1 (8 blocks, one per graph)
// accum layout: [num 8][den 8][xp 128][o1g 8]  (152 floats)
__global__ __launch_bounds__(256) void k_red(const float* __restrict__ numP, const float* __restrict__ denP,
                                             const float* __restrict__ SSp, const float* __restrict__ xpP,
                                             float* __restrict__ accum) {
  __shared__ float r1[256], r2[256];
  __shared__ float bc;
  int g = blockIdx.x, t = threadIdx.x;
  float acc = 0.f;
  for (int b = 0; b < 128; ++b) acc += SSp[((size_t)(g * 128 + b)) * 256 + t];
  float a = 0.f, d = 0.f;
  for (int i = 0; i < 4; ++i) {
    a += numP[g * 1024 + i * 256 + t];
    d += denP[g * 1024 + i * 256 + t];
  }
  r1[t] = a; r2[t] = d;
  __syncthreads();
  for (int off = 128; off > 0; off >>= 1) {
    if (t < off) { r1[t] += r1[t + off]; r2[t] += r2[t + off]; }
    __syncthreads();
  }
  if (t == 0) { accum[g] = r1[0]; accum[8 + g] = r2[0]; }
  if (t < 16) {
    float s = 0.f;
    for (int b = 0; b < 128; ++b) s += xpP[(g * 128 + b) * 16 + t];
    accum[16 + g * 16 + t] = s;
  }
  __syncthreads();
  r1[t] = acc * acc;
  __syncthreads();
  for (int off = 128; off > 0; off >>= 1) {
    if (t < off) r1[t] += r1[t + off];
    __syncthreads();
  }
  if (t == 0) bc = sqrtf(r1[0]);
  __syncthreads();
  float dv = acc / bc - (((t >> 4) == (t & 15)) ? 0.25f : 0.f);
  r1[t] = dv * dv;
  __syncthreads();
  for (int off = 128; off > 0; off >>= 1) {
    if (t < off) r1[t] += r1[t + off];
    __syncthreads();
  }
  if (t == 0) accum[144 + g] = sqrtf(r1[0]);
}

// ---------------- scalars: mc1, o1, pred (tiny)
__global__ __launch_bounds__(64) void k_final(const float* __restrict__ accum, const float* __restrict__ ncells,
                                              const float* __restrict__ Wp, const float* __restrict__ bp,
                                              float* __restrict__ dout) {
  int t = threadIdx.x;
  const float* num = accum;
  const float* den = accum + 8;
  const float* xp  = accum + 16;
  const float* o1g = accum + 144;
  if (t == 0) {
    float m = 0.f, o = 0.f;
    for (int g = 0; g < 8; ++g) { m += -num[g] / den[g]; o += o1g[g]; }
    dout[8 + (size_t)NN * 16] = m / 8.f;
    dout[8 + (size_t)NN * 16 + 1] = o / 8.f;
  }
  if (t < 8) {
    float p = bp[0];
    for (int k = 0; k < 16; ++k) p += (xp[t * 16 + k] / ncells[t]) * Wp[k];
    dout[t] = p;
  }
}

extern "C" void kernel_launch(void* const* d_in, const int* in_sizes, int n_in,
                              void* d_out, int out_size, void* d_ws, size_t ws_size,
                              hipStream_t stream) {
  const int* x            = (const int*)d_in[0];
  const int* ei           = (const int*)d_in[1];   // int32 (JAX x64 disabled)
  const float* ncells     = (const float*)d_in[3];
  const float* emb        = (const float*)d_in[4];
  const float* W2         = (const float*)d_in[5];
  const float* b2         = (const float*)d_in[6];
  const float* W3         = (const float*)d_in[7];
  const float* b3         = (const float*)d_in[8];
  const float* W1         = (const float*)d_in[9];
  const float* b1         = (const float*)d_in[10];
  const float* Wp         = (const float*)d_in[11];
  const float* bp         = (const float*)d_in[12];
  float* dout = (float*)d_out;

  // workspace layout (~58 MB); every cell fully written before read each launch (no memset).
  char* w = (char*)d_ws;
  float* accum = (float*)w;                            // 152 used, pad 160
  float2* dx   = (float2*)(accum + 160);               // N float2 (dis, x-bits)
  int* offs    = (int*)(dx + NN);                      // N
  int* cnt     = offs + NN;                            // N
  int* adj     = cnt + NN;                             // E
  float* M1    = (float*)(adj + EE);                   // 512
  _Float16* W3p = (_Float16*)(M1 + 512);               // 4096 halves
  _Float16* W1p = W3p + 4096;                          // 1024 halves
  __half2* out1h = (__half2*)(W1p + 1024);             // N*32 half2 = 32 MB
  __half* sbh  = (__half*)(out1h + (size_t)NN * 32);   // N*16 half = 8 MB
  float* numP  = (float*)(sbh + (size_t)NN * 16);      // 8192
  float* denP  = numP + 8192;                          // 8192
  float* SSp   = denP + 8192;                          // 1024*256
  float* xpP   = SSp + 1024 * 256;                     // 1024*16
  int* histT   = (int*)(xpP + 1024 * 16);              // 8*64*64
  int* baseB   = histT + 8 * 64 * 64;                  // 8*64*64
  int* winOff  = baseB + 8 * 64 * 64;                  // 512
  int* winCnt  = winOff + 512;                         // 512
  int* binned  = winCnt + 512;                         // E

  k_histprep<<<534, 256, 0, stream>>>(ei, histT, emb, W2, W3, W1, M1, W3p, W1p);
  k_hscan <<<8, 64, 0, stream>>>(histT, winOff, winCnt, baseB);
  k_scat  <<<512, 256, 0, stream>>>(ei, baseB, binned);
  k_build <<<512, 512, 0, stream>>>(binned, winOff, winCnt, x, offs, cnt, dx, adj);
  k_wout1 <<<512, 512, 0, stream>>>(binned, winOff, winCnt, dx, M1, b2, out1h);
  k_layer2<<<16384, 256, 0, stream>>>(adj, offs, cnt, dx, out1h, W3p, b3, W1p, b1, dout, sbh);
  k_num   <<<8192, 256, 0, stream>>>(adj, offs, cnt, (const __half2*)sbh, numP, denP);
  k_ssden <<<1024, 256, 0, stream>>>((const __half2*)sbh, xpP, SSp);
  k_red   <<<8, 256, 0, stream>>>(numP, denP, SSp, xpP, accum);
  k_final <<<1, 64, 0, stream>>>(accum, ncells, Wp, bp, dout);
}